// Round 10
// baseline (210.699 us; speedup 1.0000x reference)
//
#include <hip/hip_runtime.h>
#include <math.h>

#define B_ 2
#define N_ 2048
#define E_ 1024
#define H_ 16
#define D_ 64

typedef unsigned short US;
typedef _Float16 h16x8 __attribute__((ext_vector_type(8)));
typedef _Float16 h16x4 __attribute__((ext_vector_type(4)));
typedef __fp16 fp16x2 __attribute__((ext_vector_type(2)));
typedef float f32x4 __attribute__((ext_vector_type(4)));
typedef float f32x16 __attribute__((ext_vector_type(16)));
#define MFMA16F(a,b,c)  __builtin_amdgcn_mfma_f32_16x16x32_f16(a,b,c,0,0,0)
#define MFMA161(a,b,c)  __builtin_amdgcn_mfma_f32_16x16x16f16(a,b,c,0,0,0)
#define MFMA32F(a,b,c)  __builtin_amdgcn_mfma_f32_32x32x16_f16(a,b,c,0,0,0)
#define SCL  11.5415603828f   // 8 * log2(e), folded into Q at the QKV-GEMM epilogue

union HU { _Float16 h; US u; };
__device__ __forceinline__ US f2h(float f){ HU x; x.h = (_Float16)f; return x.u; }
__device__ __forceinline__ unsigned pkrtz(float a, float b){
  union { fp16x2 h; unsigned u; } x;
  x.h = __builtin_amdgcn_cvt_pkrtz(a, b);
  return x.u;
}

union U8 { US u[8]; uint4 v; };
union U4 { US u[4]; uint2 v; };
union UPA { unsigned u[2]; h16x4 h; };

// async global->LDS, 16B/lane; LDS dest = wave-uniform base + lane*16 (no padding possible)
__device__ __forceinline__ void glds16(const US* g, US* l){
  __builtin_amdgcn_global_load_lds(
    (const __attribute__((address_space(1))) unsigned int*)(const void*)g,
    (__attribute__((address_space(3))) unsigned int*)(void*)l, 16, 0, 0);
}

// ---- fused convert: x (2048 blocks) + Wq/Wk/Wv/Wo (512 blocks each) fp32->fp16 ----
__global__ __launch_bounds__(256) void conv_all(
    const float* __restrict__ x,
    const float* __restrict__ w0, const float* __restrict__ w1,
    const float* __restrict__ w2, const float* __restrict__ w3,
    US* __restrict__ xh, US* __restrict__ Wall)
{
  const int id = blockIdx.x;
  const float* s; US* d; size_t off;
  if (id < 2048) { s = x; d = xh; off = (size_t)id*2048; }
  else {
    int j = id - 2048, wsel = j>>9;
    off = (size_t)(j&511)*2048;
    s = (wsel==0)?w0:(wsel==1)?w1:(wsel==2)?w2:w3;
    d = Wall + (size_t)wsel*1048576;
  }
  size_t i = off + (size_t)threadIdx.x*8;
  float f[8];
  *(float4*)&f[0] = *(const float4*)&s[i];
  *(float4*)&f[4] = *(const float4*)&s[i+4];
  U8 h;
  #pragma unroll
  for (int j=0;j<8;++j) h.u[j] = f2h(f[j]);
  *(uint4*)&d[i] = h.v;
}

// ---- QKV GEMM (R13-proven): 128x128 tile, BK=32, z-sliced (z selects Wq/Wk/Wv).
// Grid (8,32,3) = 768 blocks = exactly 3 blocks/CU at (256,3) -> single occupancy round.
// Outputs: z=0 Q*SCL fp16 [B,H,N,D]; z=1 K fp16 [B,H,N,D]; z=2 V fp16 [B,H,D,N].
// R16 lesson: BK=64 (fewer barriers, swizzled LDS) measured WORSE.
__global__ __launch_bounds__(256,3) void qkv_gemm(
    const US* __restrict__ A, const US* __restrict__ Wall,
    const float* __restrict__ bq, const float* __restrict__ bk, const float* __restrict__ bv,
    US* __restrict__ Qf, US* __restrict__ Kf, US* __restrict__ Vtb)
{
  __shared__ __align__(16) US sA[128*32];
  __shared__ __align__(16) US sW[128*32];
  const int z = blockIdx.z;
  const US* W = Wall + (size_t)z*1048576;
  const float* bias = (z==0)?bq:(z==1)?bk:bv;

  const int t = threadIdx.x;
  const int w = t>>6, lane = t&63;
  const int q = lane>>4, c = lane&15;
  const int mq = (w>>1)*64, nq = (w&1)*64;
  const int gm0 = blockIdx.y*128, gn0 = blockIdx.x*128;
  const int r16 = lane>>2, seg = lane&3;    // staging: 4 lanes/row, 16B each

  f32x4 acc[4][4] = {};
  for (int kb = 0; kb < 1024; kb += 32) {
    #pragma unroll
    for (int p=0;p<2;++p){
      int rb = (w*2+p)*16;
      glds16(&A[(size_t)(gm0 + rb + r16)*1024 + kb + seg*8], &sA[rb*32]);
      glds16(&W[(size_t)(gn0 + rb + r16)*1024 + kb + seg*8], &sW[rb*32]);
    }
    __syncthreads();
    h16x8 af[4], wf[4];
    #pragma unroll
    for (int rt=0;rt<4;++rt) af[rt] = *(const h16x8*)&sA[(mq+rt*16+c)*32 + q*8];
    #pragma unroll
    for (int ct=0;ct<4;++ct) wf[ct] = *(const h16x8*)&sW[(nq+ct*16+c)*32 + q*8];
    #pragma unroll
    for (int rt=0;rt<4;++rt)
      #pragma unroll
      for (int ct=0;ct<4;++ct)
        acc[rt][ct] = MFMA16F(af[rt], wf[ct], acc[rt][ct]);
    __syncthreads();
  }
  #pragma unroll
  for (int rt=0;rt<4;++rt)
  #pragma unroll
  for (int ct=0;ct<4;++ct) {
    int col = gn0 + nq + ct*16 + c;
    float bv_ = bias[col];
    int rowb = gm0 + mq + rt*16 + q*4;
    int hh = col>>6, d = col & 63;
    if (z==2) {
      int b = rowb>>11, n = rowb & (N_-1);
      U4 pk;
      #pragma unroll
      for (int r=0;r<4;++r) pk.u[r] = f2h(acc[rt][ct][r] + bv_);
      *(uint2*)&Vtb[((size_t)(b*H_+hh)*D_ + d)*N_ + n] = pk.v;
    } else {
      US* dst = (z==0) ? Qf : Kf;
      #pragma unroll
      for (int r=0;r<4;++r) {
        int row = rowb + r;
        float v = acc[rt][ct][r] + bv_;
        if (z==0) v *= SCL;      // fold softmax scale + log2e into Q (fp32, pre-rounding)
        int b = row>>11, n = row & (N_-1);
        dst[((size_t)(b*H_+hh)*N_+n)*D_ + d] = f2h(v);
      }
    }
  }
}

// ---- O GEMM, R19: 64x64 tiles via 32x32 MFMA (v_mfma_f32_32x32x16_f16).
// Per wave-iter: 4 ds_read_b128 + 2 MFMA (was 6 + 8) at identical FLOPs/staging:
// -33% LDS-read instrs, -59% MFMA issue cycles. Bank profile of the 32x32 read
// pattern (32 rows x 64B stride, k-half by lane>>5) == the 16x16 pattern's (2x
// imbalance, unchanged). A-frag: lane reads A[row=l&31][kc*16+(l>>5)*8 ..+8].
// C-layout (m74/m101): col=lane&31, row=(reg&3)+8*(reg>>2)+4*(lane>>5).
// Grid (16,64)=1024 blocks, (256,8), VGPR ~40 -> 4 blocks/CU = 16 waves/CU kept.
__global__ __launch_bounds__(256,8) void o_gemm(
    const US* __restrict__ A, const US* __restrict__ W,
    const float* __restrict__ bias, float* __restrict__ out)
{
  __shared__ __align__(16) US sA[64*32];
  __shared__ __align__(16) US sW[64*32];
  const int t = threadIdx.x;
  const int w = t>>6, lane = t&63;
  const int r31 = lane&31, hi = lane>>5;
  const int wr = (w>>1)*32, wc = (w&1)*32;
  const int gm0 = blockIdx.y*64, gn0 = blockIdx.x*64;
  const int r4 = lane>>2, seg = lane&3;   // staging: per wave 16 rows x 4 chunks of 16B

  f32x16 acc = {};
  for (int kb = 0; kb < 1024; kb += 32) {
    glds16(&A[(size_t)(gm0 + w*16 + r4)*1024 + kb + seg*8], &sA[(w*16)*32]);
    glds16(&W[(size_t)(gn0 + w*16 + r4)*1024 + kb + seg*8], &sW[(w*16)*32]);
    __syncthreads();
    #pragma unroll
    for (int kc=0; kc<2; ++kc){
      h16x8 af = *(const h16x8*)&sA[(wr + r31)*32 + kc*16 + hi*8];
      h16x8 wf = *(const h16x8*)&sW[(wc + r31)*32 + kc*16 + hi*8];
      acc = MFMA32F(af, wf, acc);
    }
    __syncthreads();
  }
  const int col = gn0 + wc + r31;
  const float bv_ = bias[col];
  #pragma unroll
  for (int reg=0; reg<16; ++reg){
    int row = gm0 + wr + (reg&3) + 8*(reg>>2) + 4*hi;
    out[(size_t)row*1024 + col] = acc[reg] + bv_;
  }
}

// ---- Flash attention (R13-exact, the session's verified best: attn 75.0us, no spill).
// 512-thread blocks (8 waves), transposed-S, 128-key tiles; wave owns 16 q-rows.
// Register-P PV via K=16 v_mfma_f32_16x16x16f16 (A-frag key layout 4q+j == S^T
// C-layout -> P never touches LDS). Double-buffered K/V in LDS (71.7 KB, 2 blocks/CU
// grid-capped). T14 reg-staged: global->reg at loop top (full tile compute covers
// latency), ds_write into buf^1 at bottom, ONE barrier per iteration.
// Defer-max THR=8 (exp2 domain; P <= 2^8 fp16-safe). max3-friendly fmax tree.
// Session lessons pinned here: merging QK(t+1) into PV(t) -> spill (R14); glds16+
// early-barrier -> lost latency cover (R12); V XOR-swizzle / V-regroup -> conflicts
// (R12/R17); K-direct-from-global -> vmcnt on critical path (R16); 4-wave 64-key
// blocks -> overhead doubles (R15); dual-path softmax -> spill (R17); 3 blocks/CU
// needs (512,6)=85 VGPR < ~95 demand -> spill (R10); K unpadded via glds16 = 16-way
// conflict (G4 trap) -> K must stay reg-staged at KSTR2=72.
#define KSTR2 72   // K tile row stride
#define VSTR  136  // Vt row stride (128 keys + 8)
__global__ __launch_bounds__(512,4) void attn(
    const US* __restrict__ Qf, const US* __restrict__ Kf, const US* __restrict__ Vt,
    US* __restrict__ Hout)
{
  __shared__ __align__(16) US sK [2][128*KSTR2];
  __shared__ __align__(16) US sVt[2][64*VSTR];
  const int t = threadIdx.x;
  const int w = t>>6, lane = t&63, q = lane>>4, c = lane&15;
  const int id = blockIdx.x;
  // XCD swizzle: 16 q-tiles of one (b,h) stay on one XCD (id%8 stable across them)
  const int bh = ((id & 7) << 2) | ((id >> 3) & 3);
  const int n0 = (id >> 5) * 128;
  const US* Kp = Kf + (size_t)bh * (N_*D_);
  const US* Vp = Vt + (size_t)bh * (D_*N_);

  // Q B-frags in registers (pre-scaled): rows n0 + w*16 + c
  const size_t qoff = (size_t)bh*(N_*D_) + (size_t)(n0 + w*16 + c)*D_;
  h16x8 qb0 = *(const h16x8*)&Qf[qoff + q*8];
  h16x8 qb1 = *(const h16x8*)&Qf[qoff + 32 + q*8];
  h16x4 vones;
  #pragma unroll
  for (int j=0;j<4;++j) vones[j] = (_Float16)1.0f;

  float mi = -INFINITY;
  f32x4 o[5] = {};           // 0..3 = output d-cols; 4 = l accumulator (ones-row)

  const int kr = t>>3, kc8 = (t&7)*8;     // K staging: 8 thr/row, 64 rows/pass
  const int vr = t>>4, vc8 = (t&15)*8;    // Vt staging: 16 thr/row, 32 rows/pass

  // prologue: stage tile 0 into buffer 0
  #pragma unroll
  for (int p=0;p<2;++p){
    int r = p*64 + kr;
    *(uint4*)&sK[0][r*KSTR2 + kc8] = *(const uint4*)&Kp[(size_t)r*D_ + kc8];
  }
  #pragma unroll
  for (int p=0;p<2;++p){
    int r = p*32 + vr;
    *(uint4*)&sVt[0][r*VSTR + vc8] = *(const uint4*)&Vp[(size_t)r*N_ + vc8];
  }
  __syncthreads();

  for (int mt=0; mt<16; ++mt) {
    const int cur = mt&1;
    // T14 issue-early: next tile's global loads into regs; vmcnt waited only at the
    // ds_write at the bottom -- QK+softmax+PV covers the latency.
    uint4 kreg[2], vreg[2];
    if (mt < 15){
      const int m1 = (mt+1)*128;
      #pragma unroll
      for (int p=0;p<2;++p)
        kreg[p] = *(const uint4*)&Kp[(size_t)(m1 + p*64 + kr)*D_ + kc8];
      #pragma unroll
      for (int p=0;p<2;++p)
        vreg[p] = *(const uint4*)&Vp[(size_t)(p*32 + vr)*N_ + m1 + vc8];
    }

    // S^T: key f-frags (A=K rows f*16+c), qrow = B-col; already in exp2 domain
    f32x4 s[8];
    __builtin_amdgcn_s_setprio(1);
    #pragma unroll
    for (int f=0; f<8; ++f){
      h16x8 k0 = *(const h16x8*)&sK[cur][(f*16+c)*KSTR2 + q*8];
      h16x8 k1 = *(const h16x8*)&sK[cur][(f*16+c)*KSTR2 + 32 + q*8];
      f32x4 sv = {};
      sv = MFMA16F(k0, qb0, sv);
      sv = MFMA16F(k1, qb1, sv);
      s[f] = sv;
    }
    __builtin_amdgcn_s_setprio(0);

    // softmax: keys lane-local (32/lane); this lane's qrow = c. max3-friendly tree.
    f32x4 t1;
    #pragma unroll
    for (int j=0;j<4;++j){
      float a = fmaxf(fmaxf(s[0][j],s[1][j]),s[2][j]);
      float b = fmaxf(fmaxf(s[3][j],s[4][j]),s[5][j]);
      float d = fmaxf(fmaxf(s[6][j],s[7][j]),a);
      t1[j] = fmaxf(b,d);
    }
    float v = fmaxf(fmaxf(t1[0],t1[1]), fmaxf(t1[2],t1[3]));
    v = fmaxf(v, __shfl_xor(v, 16));
    v = fmaxf(v, __shfl_xor(v, 32));     // replicated across the 4 q-lanes
    // defer-max THR=8: rescale only when some row exceeds mi by >8 (P <= 2^8 fp16-safe)
    if (!__all(v <= mi + 8.0f)) {
      float mnew = fmaxf(mi, v);
      float alpha = exp2f(mi - mnew);
      float ar[4];
      #pragma unroll
      for (int r=0; r<4; ++r) ar[r] = __shfl(alpha, q*4+r);
      #pragma unroll
      for (int dt=0; dt<5; ++dt){        // includes the l accumulator
        o[dt][0]*=ar[0]; o[dt][1]*=ar[1]; o[dt][2]*=ar[2]; o[dt][3]*=ar[3];
      }
      mi = mnew;
    }
    // exp2 + pack P (rtz); P feeds PV directly as K=16 A-frags (keys 4q+j match the
    // S^T C-layout) -- no LDS round-trip. l comes from the ones-column MFMA.
    #pragma unroll
    for (int f=0; f<8; ++f){
      float p0 = exp2f(s[f][0]-mi);
      float p1 = exp2f(s[f][1]-mi);
      float p2 = exp2f(s[f][2]-mi);
      float p3 = exp2f(s[f][3]-mi);
      UPA pa;
      pa.u[0] = pkrtz(p0, p1);
      pa.u[1] = pkrtz(p2, p3);
      h16x4 pah = pa.h;
      __builtin_amdgcn_s_setprio(1);
      #pragma unroll
      for (int dt=0; dt<4; ++dt){
        h16x4 vf = *(const h16x4*)&sVt[cur][(dt*16+c)*VSTR + f*16 + q*4];
        o[dt] = MFMA161(pah, vf, o[dt]);
      }
      o[4] = MFMA161(pah, vones, o[4]);
      __builtin_amdgcn_s_setprio(0);
    }

    // T14 write-late: land next tile in buf^1 (last read in iter mt-1; its trailing
    // barrier already fenced it -- no extra barrier needed before these writes).
    if (mt < 15){
      #pragma unroll
      for (int p=0;p<2;++p)
        *(uint4*)&sK[cur^1][(p*64+kr)*KSTR2 + kc8] = kreg[p];
      #pragma unroll
      for (int p=0;p<2;++p)
        *(uint4*)&sVt[cur^1][(p*32+vr)*VSTR + vc8] = vreg[p];
    }
    __syncthreads();
  }

  // l is row-indexed (component r = row q*4+r): no shfl needed
  const int b = bh>>4, hh = bh&15;
  float ir[4];
  #pragma unroll
  for (int r=0; r<4; ++r) ir[r] = 1.0f / o[4][r];
  #pragma unroll
  for (int dt=0; dt<4; ++dt){
    #pragma unroll
    for (int r=0; r<4; ++r){
      int n = n0 + w*16 + q*4 + r;
      int d = dt*16 + c;
      Hout[((size_t)(b*N_+n)*H_+hh)*D_ + d] = f2h(o[dt][r] * ir[r]);  // [B,N,E] fp16
    }
  }
}

extern "C" void kernel_launch(void* const* d_in, const int* in_sizes, int n_in,
                              void* d_out, int out_size, void* d_ws, size_t ws_size,
                              hipStream_t stream)
{
  const float* x  = (const float*)d_in[0];
  const float* Wq = (const float*)d_in[1];
  const float* bq = (const float*)d_in[2];
  const float* Wk = (const float*)d_in[3];
  const float* bk = (const float*)d_in[4];
  const float* Wv = (const float*)d_in[5];
  const float* bv = (const float*)d_in[6];
  const float* Wo = (const float*)d_in[7];
  const float* bo = (const float*)d_in[8];
  US* ws  = (US*)d_ws;
  const size_t M1 = 1048576;
  US* xh   = ws;                 // 4M fp16
  US* Wall = ws + 4*M1;          // 4M: Wq,Wk,Wv,Wo fp16 contiguous
  US* Qf   = ws + 8*M1;          // 4M, [B,H,N,D], pre-scaled by 8*log2e
  US* Kf   = ws + 12*M1;         // 4M, [B,H,N,D]
  US* Vtb  = ws + 16*M1;         // 4M, [B,H,D,N]
  US* Hf   = ws + 20*M1;         // 4M, [B,N,E]  -> 48 MB total

  conv_all<<<4096, 256, 0, stream>>>(x, Wq, Wk, Wv, Wo, xh, Wall);
  qkv_gemm<<<dim3(8,32,3), 256, 0, stream>>>(xh, Wall, bq, bk, bv, Qf, Kf, Vtb);
  attn<<<512, 512, 0, stream>>>(Qf, Kf, Vtb, Hf);
  o_gemm<<<dim3(16,64), 256, 0, stream>>>(Hf, Wall + 3*M1, bo, (float*)d_out);
}

// Round 11
// 206.210 us; speedup vs baseline: 1.0218x; 1.0218x over previous
//
#include <hip/hip_runtime.h>
#include <math.h>

#define B_ 2
#define N_ 2048
#define E_ 1024
#define H_ 16
#define D_ 64

typedef unsigned short US;
typedef _Float16 h16x8 __attribute__((ext_vector_type(8)));
typedef _Float16 h16x4 __attribute__((ext_vector_type(4)));
typedef __fp16 fp16x2 __attribute__((ext_vector_type(2)));
typedef float f32x4 __attribute__((ext_vector_type(4)));
#define MFMA16F(a,b,c)  __builtin_amdgcn_mfma_f32_16x16x32_f16(a,b,c,0,0,0)
#define MFMA161(a,b,c)  __builtin_amdgcn_mfma_f32_16x16x16f16(a,b,c,0,0,0)
#define SCL  11.5415603828f   // 8 * log2(e), folded into Q at the QKV-GEMM epilogue

union HU { _Float16 h; US u; };
__device__ __forceinline__ US f2h(float f){ HU x; x.h = (_Float16)f; return x.u; }
__device__ __forceinline__ unsigned pkrtz(float a, float b){
  union { fp16x2 h; unsigned u; } x;
  x.h = __builtin_amdgcn_cvt_pkrtz(a, b);
  return x.u;
}

union U8 { US u[8]; uint4 v; };
union U4 { US u[4]; uint2 v; };
union UPA { unsigned u[2]; h16x4 h; };

// async global->LDS, 16B/lane; LDS dest = wave-uniform base + lane*16 (no padding possible)
__device__ __forceinline__ void glds16(const US* g, US* l){
  __builtin_amdgcn_global_load_lds(
    (const __attribute__((address_space(1))) unsigned int*)(const void*)g,
    (__attribute__((address_space(3))) unsigned int*)(void*)l, 16, 0, 0);
}

// ---- fused convert: x (2048 blocks) + Wq/Wk/Wv/Wo (512 blocks each) fp32->fp16 ----
__global__ __launch_bounds__(256) void conv_all(
    const float* __restrict__ x,
    const float* __restrict__ w0, const float* __restrict__ w1,
    const float* __restrict__ w2, const float* __restrict__ w3,
    US* __restrict__ xh, US* __restrict__ Wall)
{
  const int id = blockIdx.x;
  const float* s; US* d; size_t off;
  if (id < 2048) { s = x; d = xh; off = (size_t)id*2048; }
  else {
    int j = id - 2048, wsel = j>>9;
    off = (size_t)(j&511)*2048;
    s = (wsel==0)?w0:(wsel==1)?w1:(wsel==2)?w2:w3;
    d = Wall + (size_t)wsel*1048576;
  }
  size_t i = off + (size_t)threadIdx.x*8;
  float f[8];
  *(float4*)&f[0] = *(const float4*)&s[i];
  *(float4*)&f[4] = *(const float4*)&s[i+4];
  U8 h;
  #pragma unroll
  for (int j=0;j<8;++j) h.u[j] = f2h(f[j]);
  *(uint4*)&d[i] = h.v;
}

// ---- QKV GEMM (R13-proven): 128x128 tile, BK=32, z-sliced (z selects Wq/Wk/Wv).
// Grid (8,32,3) = 768 blocks = exactly 3 blocks/CU at (256,3) -> single occupancy round.
// Outputs: z=0 Q*SCL fp16 [B,H,N,D]; z=1 K fp16 [B,H,N,D]; z=2 V fp16 [B,H,D,N].
// R16 lesson: BK=64 (fewer barriers, swizzled LDS) measured WORSE.
__global__ __launch_bounds__(256,3) void qkv_gemm(
    const US* __restrict__ A, const US* __restrict__ Wall,
    const float* __restrict__ bq, const float* __restrict__ bk, const float* __restrict__ bv,
    US* __restrict__ Qf, US* __restrict__ Kf, US* __restrict__ Vtb)
{
  __shared__ __align__(16) US sA[128*32];
  __shared__ __align__(16) US sW[128*32];
  const int z = blockIdx.z;
  const US* W = Wall + (size_t)z*1048576;
  const float* bias = (z==0)?bq:(z==1)?bk:bv;

  const int t = threadIdx.x;
  const int w = t>>6, lane = t&63;
  const int q = lane>>4, c = lane&15;
  const int mq = (w>>1)*64, nq = (w&1)*64;
  const int gm0 = blockIdx.y*128, gn0 = blockIdx.x*128;
  const int r16 = lane>>2, seg = lane&3;    // staging: 4 lanes/row, 16B each

  f32x4 acc[4][4] = {};
  for (int kb = 0; kb < 1024; kb += 32) {
    #pragma unroll
    for (int p=0;p<2;++p){
      int rb = (w*2+p)*16;
      glds16(&A[(size_t)(gm0 + rb + r16)*1024 + kb + seg*8], &sA[rb*32]);
      glds16(&W[(size_t)(gn0 + rb + r16)*1024 + kb + seg*8], &sW[rb*32]);
    }
    __syncthreads();
    h16x8 af[4], wf[4];
    #pragma unroll
    for (int rt=0;rt<4;++rt) af[rt] = *(const h16x8*)&sA[(mq+rt*16+c)*32 + q*8];
    #pragma unroll
    for (int ct=0;ct<4;++ct) wf[ct] = *(const h16x8*)&sW[(nq+ct*16+c)*32 + q*8];
    #pragma unroll
    for (int rt=0;rt<4;++rt)
      #pragma unroll
      for (int ct=0;ct<4;++ct)
        acc[rt][ct] = MFMA16F(af[rt], wf[ct], acc[rt][ct]);
    __syncthreads();
  }
  #pragma unroll
  for (int rt=0;rt<4;++rt)
  #pragma unroll
  for (int ct=0;ct<4;++ct) {
    int col = gn0 + nq + ct*16 + c;
    float bv_ = bias[col];
    int rowb = gm0 + mq + rt*16 + q*4;
    int hh = col>>6, d = col & 63;
    if (z==2) {
      int b = rowb>>11, n = rowb & (N_-1);
      U4 pk;
      #pragma unroll
      for (int r=0;r<4;++r) pk.u[r] = f2h(acc[rt][ct][r] + bv_);
      *(uint2*)&Vtb[((size_t)(b*H_+hh)*D_ + d)*N_ + n] = pk.v;
    } else {
      US* dst = (z==0) ? Qf : Kf;
      #pragma unroll
      for (int r=0;r<4;++r) {
        int row = rowb + r;
        float v = acc[rt][ct][r] + bv_;
        if (z==0) v *= SCL;      // fold softmax scale + log2e into Q (fp32, pre-rounding)
        int b = row>>11, n = row & (N_-1);
        dst[((size_t)(b*H_+hh)*N_+n)*D_ + d] = f2h(v);
      }
    }
  }
}

// ---- O GEMM: out = H @ Wo^T + bo, fp32 row-major [4096][1024].
// 64x64 tiles via 16x16 MFMA, grid (16,64)=1024 blocks, (256,8) -> 4 blocks/CU
// = 16 waves/CU. R19 lesson: the 32x32-MFMA retile regressed (+4us) -- its 64B-row-
// stride b128 reads alternate between only 2 bank groups (16*r31 mod 32) -> ~8-way
// serialization that erased the MFMA-issue savings. 16x16 layout retained.
__global__ __launch_bounds__(256,8) void o_gemm(
    const US* __restrict__ A, const US* __restrict__ W,
    const float* __restrict__ bias, float* __restrict__ out)
{
  __shared__ __align__(16) US sA[64*32];
  __shared__ __align__(16) US sW[64*32];
  const int t = threadIdx.x;
  const int w = t>>6, lane = t&63;
  const int q = lane>>4, c = lane&15;
  const int wr = (w>>1)*32, wc = (w&1)*32;
  const int gm0 = blockIdx.y*64, gn0 = blockIdx.x*64;
  const int r4 = lane>>2, seg = lane&3;   // per wave: 16 rows x 4 chunks of 16B

  f32x4 acc[2][2] = {};
  for (int kb = 0; kb < 1024; kb += 32) {
    glds16(&A[(size_t)(gm0 + w*16 + r4)*1024 + kb + seg*8], &sA[(w*16)*32]);
    glds16(&W[(size_t)(gn0 + w*16 + r4)*1024 + kb + seg*8], &sW[(w*16)*32]);
    __syncthreads();
    h16x8 af[2], wf[2];
    #pragma unroll
    for (int rt=0;rt<2;++rt) af[rt] = *(const h16x8*)&sA[(wr+rt*16+c)*32 + q*8];
    #pragma unroll
    for (int ct=0;ct<2;++ct) wf[ct] = *(const h16x8*)&sW[(wc+ct*16+c)*32 + q*8];
    #pragma unroll
    for (int rt=0;rt<2;++rt)
      #pragma unroll
      for (int ct=0;ct<2;++ct)
        acc[rt][ct] = MFMA16F(af[rt], wf[ct], acc[rt][ct]);
    __syncthreads();
  }
  #pragma unroll
  for (int rt=0; rt<2; ++rt)
  #pragma unroll
  for (int ct=0; ct<2; ++ct) {
    int col = gn0 + wc + ct*16 + c;
    float bv_ = bias[col];
    int rowb = gm0 + wr + rt*16 + q*4;
    #pragma unroll
    for (int r=0;r<4;++r)
      out[(size_t)(rowb+r)*1024 + col] = acc[rt][ct][r] + bv_;
  }
}

// ---- Flash attention (R13-exact, the session's verified best: attn 75.0us, no spill).
// 512-thread blocks (8 waves), transposed-S, 128-key tiles; wave owns 16 q-rows.
// Register-P PV via K=16 v_mfma_f32_16x16x16f16 (A-frag key layout 4q+j == S^T
// C-layout -> P never touches LDS). Double-buffered K/V in LDS (71.7 KB; binding
// constraints are LDS + grid=512 -> 2 blocks/CU, NOT registers: VGPR_Count=52).
// T14 reg-staged: global->reg at loop top (full tile compute covers latency),
// ds_write into buf^1 at bottom, ONE barrier per iteration.
// Defer-max THR=8 (exp2 domain; P <= 2^8 fp16-safe). max3-friendly fmax tree.
// Session lessons pinned here: merging QK(t+1) into PV(t) -> spill (R14); glds16+
// early-barrier -> lost latency cover (R12); V XOR-swizzle / V-regroup -> conflicts
// (R12/R17); K-direct-from-global -> vmcnt on critical path (R16); 4-wave 64-key
// blocks -> overhead doubles (R15); dual-path softmax -> spill (R17); single-K-buffer
// frees LDS but grid=512 still caps 2 blocks/CU; q-tile<128 is the only way to more
// blocks and it measured worse (R15). Structure converged at this operating point.
#define KSTR2 72   // K tile row stride
#define VSTR  136  // Vt row stride (128 keys + 8)
__global__ __launch_bounds__(512,4) void attn(
    const US* __restrict__ Qf, const US* __restrict__ Kf, const US* __restrict__ Vt,
    US* __restrict__ Hout)
{
  __shared__ __align__(16) US sK [2][128*KSTR2];
  __shared__ __align__(16) US sVt[2][64*VSTR];
  const int t = threadIdx.x;
  const int w = t>>6, lane = t&63, q = lane>>4, c = lane&15;
  const int id = blockIdx.x;
  // XCD swizzle: 16 q-tiles of one (b,h) stay on one XCD (id%8 stable across them)
  const int bh = ((id & 7) << 2) | ((id >> 3) & 3);
  const int n0 = (id >> 5) * 128;
  const US* Kp = Kf + (size_t)bh * (N_*D_);
  const US* Vp = Vt + (size_t)bh * (D_*N_);

  // Q B-frags in registers (pre-scaled): rows n0 + w*16 + c
  const size_t qoff = (size_t)bh*(N_*D_) + (size_t)(n0 + w*16 + c)*D_;
  h16x8 qb0 = *(const h16x8*)&Qf[qoff + q*8];
  h16x8 qb1 = *(const h16x8*)&Qf[qoff + 32 + q*8];
  h16x4 vones;
  #pragma unroll
  for (int j=0;j<4;++j) vones[j] = (_Float16)1.0f;

  float mi = -INFINITY;
  f32x4 o[5] = {};           // 0..3 = output d-cols; 4 = l accumulator (ones-row)

  const int kr = t>>3, kc8 = (t&7)*8;     // K staging: 8 thr/row, 64 rows/pass
  const int vr = t>>4, vc8 = (t&15)*8;    // Vt staging: 16 thr/row, 32 rows/pass

  // prologue: stage tile 0 into buffer 0
  #pragma unroll
  for (int p=0;p<2;++p){
    int r = p*64 + kr;
    *(uint4*)&sK[0][r*KSTR2 + kc8] = *(const uint4*)&Kp[(size_t)r*D_ + kc8];
  }
  #pragma unroll
  for (int p=0;p<2;++p){
    int r = p*32 + vr;
    *(uint4*)&sVt[0][r*VSTR + vc8] = *(const uint4*)&Vp[(size_t)r*N_ + vc8];
  }
  __syncthreads();

  for (int mt=0; mt<16; ++mt) {
    const int cur = mt&1;
    // T14 issue-early: next tile's global loads into regs; vmcnt waited only at the
    // ds_write at the bottom -- QK+softmax+PV covers the latency.
    uint4 kreg[2], vreg[2];
    if (mt < 15){
      const int m1 = (mt+1)*128;
      #pragma unroll
      for (int p=0;p<2;++p)
        kreg[p] = *(const uint4*)&Kp[(size_t)(m1 + p*64 + kr)*D_ + kc8];
      #pragma unroll
      for (int p=0;p<2;++p)
        vreg[p] = *(const uint4*)&Vp[(size_t)(p*32 + vr)*N_ + m1 + vc8];
    }

    // S^T: key f-frags (A=K rows f*16+c), qrow = B-col; already in exp2 domain
    f32x4 s[8];
    __builtin_amdgcn_s_setprio(1);
    #pragma unroll
    for (int f=0; f<8; ++f){
      h16x8 k0 = *(const h16x8*)&sK[cur][(f*16+c)*KSTR2 + q*8];
      h16x8 k1 = *(const h16x8*)&sK[cur][(f*16+c)*KSTR2 + 32 + q*8];
      f32x4 sv = {};
      sv = MFMA16F(k0, qb0, sv);
      sv = MFMA16F(k1, qb1, sv);
      s[f] = sv;
    }
    __builtin_amdgcn_s_setprio(0);

    // softmax: keys lane-local (32/lane); this lane's qrow = c. max3-friendly tree.
    f32x4 t1;
    #pragma unroll
    for (int j=0;j<4;++j){
      float a = fmaxf(fmaxf(s[0][j],s[1][j]),s[2][j]);
      float b = fmaxf(fmaxf(s[3][j],s[4][j]),s[5][j]);
      float d = fmaxf(fmaxf(s[6][j],s[7][j]),a);
      t1[j] = fmaxf(b,d);
    }
    float v = fmaxf(fmaxf(t1[0],t1[1]), fmaxf(t1[2],t1[3]));
    v = fmaxf(v, __shfl_xor(v, 16));
    v = fmaxf(v, __shfl_xor(v, 32));     // replicated across the 4 q-lanes
    // defer-max THR=8: rescale only when some row exceeds mi by >8 (P <= 2^8 fp16-safe)
    if (!__all(v <= mi + 8.0f)) {
      float mnew = fmaxf(mi, v);
      float alpha = exp2f(mi - mnew);
      float ar[4];
      #pragma unroll
      for (int r=0; r<4; ++r) ar[r] = __shfl(alpha, q*4+r);
      #pragma unroll
      for (int dt=0; dt<5; ++dt){        // includes the l accumulator
        o[dt][0]*=ar[0]; o[dt][1]*=ar[1]; o[dt][2]*=ar[2]; o[dt][3]*=ar[3];
      }
      mi = mnew;
    }
    // exp2 + pack P (rtz); P feeds PV directly as K=16 A-frags (keys 4q+j match the
    // S^T C-layout) -- no LDS round-trip. l comes from the ones-column MFMA.
    #pragma unroll
    for (int f=0; f<8; ++f){
      float p0 = exp2f(s[f][0]-mi);
      float p1 = exp2f(s[f][1]-mi);
      float p2 = exp2f(s[f][2]-mi);
      float p3 = exp2f(s[f][3]-mi);
      UPA pa;
      pa.u[0] = pkrtz(p0, p1);
      pa.u[1] = pkrtz(p2, p3);
      h16x4 pah = pa.h;
      __builtin_amdgcn_s_setprio(1);
      #pragma unroll
      for (int dt=0; dt<4; ++dt){
        h16x4 vf = *(const h16x4*)&sVt[cur][(dt*16+c)*VSTR + f*16 + q*4];
        o[dt] = MFMA161(pah, vf, o[dt]);
      }
      o[4] = MFMA161(pah, vones, o[4]);
      __builtin_amdgcn_s_setprio(0);
    }

    // T14 write-late: land next tile in buf^1 (last read in iter mt-1; its trailing
    // barrier already fenced it -- no extra barrier needed before these writes).
    if (mt < 15){
      #pragma unroll
      for (int p=0;p<2;++p)
        *(uint4*)&sK[cur^1][(p*64+kr)*KSTR2 + kc8] = kreg[p];
      #pragma unroll
      for (int p=0;p<2;++p)
        *(uint4*)&sVt[cur^1][(p*32+vr)*VSTR + vc8] = vreg[p];
    }
    __syncthreads();
  }

  // l is row-indexed (component r = row q*4+r): no shfl needed
  const int b = bh>>4, hh = bh&15;
  float ir[4];
  #pragma unroll
  for (int r=0; r<4; ++r) ir[r] = 1.0f / o[4][r];
  #pragma unroll
  for (int dt=0; dt<4; ++dt){
    #pragma unroll
    for (int r=0; r<4; ++r){
      int n = n0 + w*16 + q*4 + r;
      int d = dt*16 + c;
      Hout[((size_t)(b*N_+n)*H_+hh)*D_ + d] = f2h(o[dt][r] * ir[r]);  // [B,N,E] fp16
    }
  }
}

extern "C" void kernel_launch(void* const* d_in, const int* in_sizes, int n_in,
                              void* d_out, int out_size, void* d_ws, size_t ws_size,
                              hipStream_t stream)
{
  const float* x  = (const float*)d_in[0];
  const float* Wq = (const float*)d_in[1];
  const float* bq = (const float*)d_in[2];
  const float* Wk = (const float*)d_in[3];
  const float* bk = (const float*)d_in[4];
  const float* Wv = (const float*)d_in[5];
  const float* bv = (const float*)d_in[6];
  const float* Wo = (const float*)d_in[7];
  const float* bo = (const float*)d_in[8];
  US* ws  = (US*)d_ws;
  const size_t M1 = 1048576;
  US* xh   = ws;                 // 4M fp16
  US* Wall = ws + 4*M1;          // 4M: Wq,Wk,Wv,Wo fp16 contiguous
  US* Qf   = ws + 8*M1;          // 4M, [B,H,N,D], pre-scaled by 8*log2e
  US* Kf   = ws + 12*M1;         // 4M, [B,H,N,D]
  US* Vtb  = ws + 16*M1;         // 4M, [B,H,D,N]
  US* Hf   = ws + 20*M1;         // 4M, [B,N,E]  -> 48 MB total

  conv_all<<<4096, 256, 0, stream>>>(x, Wq, Wk, Wv, Wo, xh, Wall);
  qkv_gemm<<<dim3(8,32,3), 256, 0, stream>>>(xh, Wall, bq, bk, bv, Qf, Kf, Vtb);
  attn<<<512, 512, 0, stream>>>(Qf, Kf, Vtb, Hf);
  o_gemm<<<dim3(16,64), 256, 0, stream>>>(Hf, Wall + 3*M1, bo, (float*)d_out);
}

// Round 12
// 205.315 us; speedup vs baseline: 1.0262x; 1.0044x over previous
//
#include <hip/hip_runtime.h>
#include <math.h>

#define B_ 2
#define N_ 2048
#define E_ 1024
#define H_ 16
#define D_ 64

typedef unsigned short US;
typedef _Float16 h16x8 __attribute__((ext_vector_type(8)));
typedef _Float16 h16x4 __attribute__((ext_vector_type(4)));
typedef __fp16 fp16x2 __attribute__((ext_vector_type(2)));
typedef float f32x4 __attribute__((ext_vector_type(4)));
#define MFMA16F(a,b,c)  __builtin_amdgcn_mfma_f32_16x16x32_f16(a,b,c,0,0,0)
#define MFMA161(a,b,c)  __builtin_amdgcn_mfma_f32_16x16x16f16(a,b,c,0,0,0)
#define SCL  11.5415603828f   // 8 * log2(e), folded into Q at the QKV-GEMM epilogue

union HU { _Float16 h; US u; };
__device__ __forceinline__ US f2h(float f){ HU x; x.h = (_Float16)f; return x.u; }
__device__ __forceinline__ unsigned pkrtz(float a, float b){
  union { fp16x2 h; unsigned u; } x;
  x.h = __builtin_amdgcn_cvt_pkrtz(a, b);
  return x.u;
}

union U8 { US u[8]; uint4 v; };
union U4 { US u[4]; uint2 v; };
union UPA { unsigned u[2]; h16x4 h; };

// async global->LDS, 16B/lane; LDS dest = wave-uniform base + lane*16 (no padding possible)
__device__ __forceinline__ void glds16(const US* g, US* l){
  __builtin_amdgcn_global_load_lds(
    (const __attribute__((address_space(1))) unsigned int*)(const void*)g,
    (__attribute__((address_space(3))) unsigned int*)(void*)l, 16, 0, 0);
}

// ---- fused convert: x (2048 blocks) + Wq/Wk/Wv/Wo (512 blocks each) fp32->fp16 ----
__global__ __launch_bounds__(256) void conv_all(
    const float* __restrict__ x,
    const float* __restrict__ w0, const float* __restrict__ w1,
    const float* __restrict__ w2, const float* __restrict__ w3,
    US* __restrict__ xh, US* __restrict__ Wall)
{
  const int id = blockIdx.x;
  const float* s; US* d; size_t off;
  if (id < 2048) { s = x; d = xh; off = (size_t)id*2048; }
  else {
    int j = id - 2048, wsel = j>>9;
    off = (size_t)(j&511)*2048;
    s = (wsel==0)?w0:(wsel==1)?w1:(wsel==2)?w2:w3;
    d = Wall + (size_t)wsel*1048576;
  }
  size_t i = off + (size_t)threadIdx.x*8;
  float f[8];
  *(float4*)&f[0] = *(const float4*)&s[i];
  *(float4*)&f[4] = *(const float4*)&s[i+4];
  U8 h;
  #pragma unroll
  for (int j=0;j<8;++j) h.u[j] = f2h(f[j]);
  *(uint4*)&d[i] = h.v;
}

// ---- QKV GEMM (R13-proven): 128x128 tile, BK=32, z-sliced (z selects Wq/Wk/Wv).
// Grid (8,32,3) = 768 blocks = exactly 3 blocks/CU at (256,3) -> single occupancy round.
// Outputs: z=0 Q*SCL fp16 [B,H,N,D]; z=1 K fp16 [B,H,N,D]; z=2 V fp16 [B,H,D,N].
// R16 lesson: BK=64 (fewer barriers, swizzled LDS) measured WORSE.
__global__ __launch_bounds__(256,3) void qkv_gemm(
    const US* __restrict__ A, const US* __restrict__ Wall,
    const float* __restrict__ bq, const float* __restrict__ bk, const float* __restrict__ bv,
    US* __restrict__ Qf, US* __restrict__ Kf, US* __restrict__ Vtb)
{
  __shared__ __align__(16) US sA[128*32];
  __shared__ __align__(16) US sW[128*32];
  const int z = blockIdx.z;
  const US* W = Wall + (size_t)z*1048576;
  const float* bias = (z==0)?bq:(z==1)?bk:bv;

  const int t = threadIdx.x;
  const int w = t>>6, lane = t&63;
  const int q = lane>>4, c = lane&15;
  const int mq = (w>>1)*64, nq = (w&1)*64;
  const int gm0 = blockIdx.y*128, gn0 = blockIdx.x*128;
  const int r16 = lane>>2, seg = lane&3;    // staging: 4 lanes/row, 16B each

  f32x4 acc[4][4] = {};
  for (int kb = 0; kb < 1024; kb += 32) {
    #pragma unroll
    for (int p=0;p<2;++p){
      int rb = (w*2+p)*16;
      glds16(&A[(size_t)(gm0 + rb + r16)*1024 + kb + seg*8], &sA[rb*32]);
      glds16(&W[(size_t)(gn0 + rb + r16)*1024 + kb + seg*8], &sW[rb*32]);
    }
    __syncthreads();
    h16x8 af[4], wf[4];
    #pragma unroll
    for (int rt=0;rt<4;++rt) af[rt] = *(const h16x8*)&sA[(mq+rt*16+c)*32 + q*8];
    #pragma unroll
    for (int ct=0;ct<4;++ct) wf[ct] = *(const h16x8*)&sW[(nq+ct*16+c)*32 + q*8];
    #pragma unroll
    for (int rt=0;rt<4;++rt)
      #pragma unroll
      for (int ct=0;ct<4;++ct)
        acc[rt][ct] = MFMA16F(af[rt], wf[ct], acc[rt][ct]);
    __syncthreads();
  }
  #pragma unroll
  for (int rt=0;rt<4;++rt)
  #pragma unroll
  for (int ct=0;ct<4;++ct) {
    int col = gn0 + nq + ct*16 + c;
    float bv_ = bias[col];
    int rowb = gm0 + mq + rt*16 + q*4;
    int hh = col>>6, d = col & 63;
    if (z==2) {
      int b = rowb>>11, n = rowb & (N_-1);
      U4 pk;
      #pragma unroll
      for (int r=0;r<4;++r) pk.u[r] = f2h(acc[rt][ct][r] + bv_);
      *(uint2*)&Vtb[((size_t)(b*H_+hh)*D_ + d)*N_ + n] = pk.v;
    } else {
      US* dst = (z==0) ? Qf : Kf;
      #pragma unroll
      for (int r=0;r<4;++r) {
        int row = rowb + r;
        float v = acc[rt][ct][r] + bv_;
        if (z==0) v *= SCL;      // fold softmax scale + log2e into Q (fp32, pre-rounding)
        int b = row>>11, n = row & (N_-1);
        dst[((size_t)(b*H_+hh)*N_+n)*D_ + d] = f2h(v);
      }
    }
  }
}

// ---- O GEMM: out = H @ Wo^T + bo, fp32 row-major [4096][1024].
// 64x64 tiles via 16x16 MFMA, grid (16,64)=1024 blocks, (256,8) -> 4 blocks/CU
// = 16 waves/CU. R19 lesson: 32x32-MFMA retile regressed (+4us, 2-bank-group b128).
__global__ __launch_bounds__(256,8) void o_gemm(
    const US* __restrict__ A, const US* __restrict__ W,
    const float* __restrict__ bias, float* __restrict__ out)
{
  __shared__ __align__(16) US sA[64*32];
  __shared__ __align__(16) US sW[64*32];
  const int t = threadIdx.x;
  const int w = t>>6, lane = t&63;
  const int q = lane>>4, c = lane&15;
  const int wr = (w>>1)*32, wc = (w&1)*32;
  const int gm0 = blockIdx.y*64, gn0 = blockIdx.x*64;
  const int r4 = lane>>2, seg = lane&3;   // per wave: 16 rows x 4 chunks of 16B

  f32x4 acc[2][2] = {};
  for (int kb = 0; kb < 1024; kb += 32) {
    glds16(&A[(size_t)(gm0 + w*16 + r4)*1024 + kb + seg*8], &sA[(w*16)*32]);
    glds16(&W[(size_t)(gn0 + w*16 + r4)*1024 + kb + seg*8], &sW[(w*16)*32]);
    __syncthreads();
    h16x8 af[2], wf[2];
    #pragma unroll
    for (int rt=0;rt<2;++rt) af[rt] = *(const h16x8*)&sA[(wr+rt*16+c)*32 + q*8];
    #pragma unroll
    for (int ct=0;ct<2;++ct) wf[ct] = *(const h16x8*)&sW[(wc+ct*16+c)*32 + q*8];
    #pragma unroll
    for (int rt=0;rt<2;++rt)
      #pragma unroll
      for (int ct=0;ct<2;++ct)
        acc[rt][ct] = MFMA16F(af[rt], wf[ct], acc[rt][ct]);
    __syncthreads();
  }
  #pragma unroll
  for (int rt=0; rt<2; ++rt)
  #pragma unroll
  for (int ct=0; ct<2; ++ct) {
    int col = gn0 + wc + ct*16 + c;
    float bv_ = bias[col];
    int rowb = gm0 + wr + rt*16 + q*4;
    #pragma unroll
    for (int r=0;r<4;++r)
      out[(size_t)(rowb+r)*1024 + col] = acc[rt][ct][r] + bv_;
  }
}

// ---- Flash attention, R21: R13 schedule with K staged by glds16 (async global->LDS).
// Rule-#21 both-sides swizzle, R13's proven timing: glds16 K(t+1) issued at loop TOP
// into sK[cur^1] (last read at iter t-1, fenced by its bottom barrier); full tile
// compute covers the latency; the single bottom barrier's vmcnt(0) drain publishes it.
// LDS layout: linear [128][64]; LDS[row][cp] = K[row][cp ^ (row&7)] via per-lane
// inverse-swizzled GLOBAL source (chunk (lane&7)^(row&7); full 128B rows covered ->
// coalescing intact). QK read: orig chunk j at LDS cp = j^(c&7) (row&7 == c&7).
// Bank audit (read): chunk q^(c&7) over lanes -> 8 lanes per 4-bank group = wave64
// b128 minimum, conflict-free. Deletes 2 ds_write_b128/thread/tile (~half of stage-
// write LDS traffic; LDS = busiest pipe ~48%) + 16 VGPRs of kreg.
// V stays R13: reg-staged T14, VSTR=136 (V-swizzle variants measured bad, R12/R17).
// R12's glds failure was barrier-after-softmax (no cover) + V-swizzle -- not glds.
// Defer-max THR=8; register-P PV (K=16 A-frag key layout 4q+j == S^T C-layout).
#define VSTR  136  // Vt row stride (128 keys + 8)
__global__ __launch_bounds__(512,4) void attn(
    const US* __restrict__ Qf, const US* __restrict__ Kf, const US* __restrict__ Vt,
    US* __restrict__ Hout)
{
  __shared__ __align__(16) US sK [2][128*64];
  __shared__ __align__(16) US sVt[2][64*VSTR];
  const int t = threadIdx.x;
  const int w = t>>6, lane = t&63, q = lane>>4, c = lane&15;
  const int id = blockIdx.x;
  // XCD swizzle: 16 q-tiles of one (b,h) stay on one XCD (id%8 stable across them)
  const int bh = ((id & 7) << 2) | ((id >> 3) & 3);
  const int n0 = (id >> 5) * 128;
  const US* Kp = Kf + (size_t)bh * (N_*D_);
  const US* Vp = Vt + (size_t)bh * (D_*N_);

  // Q B-frags in registers (pre-scaled): rows n0 + w*16 + c
  const size_t qoff = (size_t)bh*(N_*D_) + (size_t)(n0 + w*16 + c)*D_;
  h16x8 qb0 = *(const h16x8*)&Qf[qoff + q*8];
  h16x8 qb1 = *(const h16x8*)&Qf[qoff + 32 + q*8];
  h16x4 vones;
  #pragma unroll
  for (int j=0;j<4;++j) vones[j] = (_Float16)1.0f;

  float mi = -INFINITY;
  f32x4 o[5] = {};           // 0..3 = output d-cols; 4 = l accumulator (ones-row)

  // K glds16 geometry: per wave 2 chunks of 8 rows; lane covers (row lane>>3, cp lane&7)
  const int krow = lane>>3, kcp = lane&7;
  const int vr = t>>4, vc8 = (t&15)*8;    // Vt staging: 16 thr/row, 32 rows/pass

  // prologue: stage tile 0 into buffer 0 (K async via glds16; V reg-staged)
  #pragma unroll
  for (int p=0;p<2;++p){
    int row = (w*2+p)*8 + krow;
    glds16(&Kp[(size_t)row*D_ + ((kcp ^ (row&7))<<3)], &sK[0][(w*2+p)*512]);
  }
  #pragma unroll
  for (int p=0;p<2;++p){
    int r = p*32 + vr;
    *(uint4*)&sVt[0][r*VSTR + vc8] = *(const uint4*)&Vp[(size_t)r*N_ + vc8];
  }
  __syncthreads();   // drains the glds16 vmcnt too

  for (int mt=0; mt<16; ++mt) {
    const int cur = mt&1;
    // issue-early: K(t+1) async direct-to-LDS (buf^1, fenced by iter t-1's barrier);
    // V(t+1) into regs (T14). Both covered by the full tile compute below.
    uint4 vreg[2];
    if (mt < 15){
      const int m1 = (mt+1)*128;
      #pragma unroll
      for (int p=0;p<2;++p){
        int row = (w*2+p)*8 + krow;
        glds16(&Kp[(size_t)(m1+row)*D_ + ((kcp ^ (row&7))<<3)], &sK[cur^1][(w*2+p)*512]);
      }
      #pragma unroll
      for (int p=0;p<2;++p)
        vreg[p] = *(const uint4*)&Vp[(size_t)(p*32 + vr)*N_ + m1 + vc8];
    }

    // S^T: key f-frags (A=K rows f*16+c), qrow = B-col; already in exp2 domain.
    // Swizzled read: orig chunk q / q+4 at LDS cp = chunk^(c&7).
    f32x4 s[8];
    __builtin_amdgcn_s_setprio(1);
    #pragma unroll
    for (int f=0; f<8; ++f){
      int r64 = (f*16+c)*64;
      h16x8 k0 = *(const h16x8*)&sK[cur][r64 + (((q  ) ^ (c&7))<<3)];
      h16x8 k1 = *(const h16x8*)&sK[cur][r64 + (((q+4) ^ (c&7))<<3)];
      f32x4 sv = {};
      sv = MFMA16F(k0, qb0, sv);
      sv = MFMA16F(k1, qb1, sv);
      s[f] = sv;
    }
    __builtin_amdgcn_s_setprio(0);

    // softmax: keys lane-local (32/lane); this lane's qrow = c. max3-friendly tree.
    f32x4 t1;
    #pragma unroll
    for (int j=0;j<4;++j){
      float a = fmaxf(fmaxf(s[0][j],s[1][j]),s[2][j]);
      float b = fmaxf(fmaxf(s[3][j],s[4][j]),s[5][j]);
      float d = fmaxf(fmaxf(s[6][j],s[7][j]),a);
      t1[j] = fmaxf(b,d);
    }
    float v = fmaxf(fmaxf(t1[0],t1[1]), fmaxf(t1[2],t1[3]));
    v = fmaxf(v, __shfl_xor(v, 16));
    v = fmaxf(v, __shfl_xor(v, 32));     // replicated across the 4 q-lanes
    // defer-max THR=8: rescale only when some row exceeds mi by >8 (P <= 2^8 fp16-safe)
    if (!__all(v <= mi + 8.0f)) {
      float mnew = fmaxf(mi, v);
      float alpha = exp2f(mi - mnew);
      float ar[4];
      #pragma unroll
      for (int r=0; r<4; ++r) ar[r] = __shfl(alpha, q*4+r);
      #pragma unroll
      for (int dt=0; dt<5; ++dt){        // includes the l accumulator
        o[dt][0]*=ar[0]; o[dt][1]*=ar[1]; o[dt][2]*=ar[2]; o[dt][3]*=ar[3];
      }
      mi = mnew;
    }
    // exp2 + pack P (rtz); P feeds PV directly as K=16 A-frags (keys 4q+j match the
    // S^T C-layout) -- no LDS round-trip. l comes from the ones-column MFMA.
    #pragma unroll
    for (int f=0; f<8; ++f){
      float p0 = exp2f(s[f][0]-mi);
      float p1 = exp2f(s[f][1]-mi);
      float p2 = exp2f(s[f][2]-mi);
      float p3 = exp2f(s[f][3]-mi);
      UPA pa;
      pa.u[0] = pkrtz(p0, p1);
      pa.u[1] = pkrtz(p2, p3);
      h16x4 pah = pa.h;
      __builtin_amdgcn_s_setprio(1);
      #pragma unroll
      for (int dt=0; dt<4; ++dt){
        h16x4 vf = *(const h16x4*)&sVt[cur][(dt*16+c)*VSTR + f*16 + q*4];
        o[dt] = MFMA161(pah, vf, o[dt]);
      }
      o[4] = MFMA161(pah, vones, o[4]);
      __builtin_amdgcn_s_setprio(0);
    }

    // write-late: land next V tile in buf^1 (last read in iter mt-1; its trailing
    // barrier already fenced it). The bottom barrier drains K's glds16 (vmcnt) and
    // publishes both K(t+1) and V(t+1).
    if (mt < 15){
      #pragma unroll
      for (int p=0;p<2;++p)
        *(uint4*)&sVt[cur^1][(p*32+vr)*VSTR + vc8] = vreg[p];
    }
    __syncthreads();
  }

  // l is row-indexed (component r = row q*4+r): no shfl needed
  const int b = bh>>4, hh = bh&15;
  float ir[4];
  #pragma unroll
  for (int r=0; r<4; ++r) ir[r] = 1.0f / o[4][r];
  #pragma unroll
  for (int dt=0; dt<4; ++dt){
    #pragma unroll
    for (int r=0; r<4; ++r){
      int n = n0 + w*16 + q*4 + r;
      int d = dt*16 + c;
      Hout[((size_t)(b*N_+n)*H_+hh)*D_ + d] = f2h(o[dt][r] * ir[r]);  // [B,N,E] fp16
    }
  }
}

extern "C" void kernel_launch(void* const* d_in, const int* in_sizes, int n_in,
                              void* d_out, int out_size, void* d_ws, size_t ws_size,
                              hipStream_t stream)
{
  const float* x  = (const float*)d_in[0];
  const float* Wq = (const float*)d_in[1];
  const float* bq = (const float*)d_in[2];
  const float* Wk = (const float*)d_in[3];
  const float* bk = (const float*)d_in[4];
  const float* Wv = (const float*)d_in[5];
  const float* bv = (const float*)d_in[6];
  const float* Wo = (const float*)d_in[7];
  const float* bo = (const float*)d_in[8];
  US* ws  = (US*)d_ws;
  const size_t M1 = 1048576;
  US* xh   = ws;                 // 4M fp16
  US* Wall = ws + 4*M1;          // 4M: Wq,Wk,Wv,Wo fp16 contiguous
  US* Qf   = ws + 8*M1;          // 4M, [B,H,N,D], pre-scaled by 8*log2e
  US* Kf   = ws + 12*M1;         // 4M, [B,H,N,D]
  US* Vtb  = ws + 16*M1;         // 4M, [B,H,D,N]
  US* Hf   = ws + 20*M1;         // 4M, [B,N,E]  -> 48 MB total

  conv_all<<<4096, 256, 0, stream>>>(x, Wq, Wk, Wv, Wo, xh, Wall);
  qkv_gemm<<<dim3(8,32,3), 256, 0, stream>>>(xh, Wall, bq, bk, bv, Qf, Kf, Vtb);
  attn<<<512, 512, 0, stream>>>(Qf, Kf, Vtb, Hf);
  o_gemm<<<dim3(16,64), 256, 0, stream>>>(Hf, Wall + 3*M1, bo, (float*)d_out);
}